// Round 11
// baseline (644.798 us; speedup 1.0000x reference)
//
#include <hip/hip_runtime.h>
#include <hip/hip_bf16.h>

typedef __attribute__((ext_vector_type(8)))  short short8;
typedef __attribute__((ext_vector_type(16))) float f32x16;
typedef unsigned short u16;
typedef unsigned int   u32;

__device__ __forceinline__ u16 f2b(float f){
    __hip_bfloat16 h = __float2bfloat16(f);
    u16 u; __builtin_memcpy(&u, &h, 2); return u;
}
__device__ __forceinline__ u32 pk2(float lo, float hi){
    return (u32)f2b(lo) | ((u32)f2b(hi) << 16);
}
__device__ __forceinline__ float b2f(u16 u){
    u32 w = ((u32)u) << 16; float f; __builtin_memcpy(&f, &w, 4); return f;
}

#define PART_STRIDE 8448  // 32q x 128d bf16 O^T + 32 f32 m + 32 f32 l

// S=2048, H=32, HKV=8, G=4, D=128, DIFF_BS=32
// R8: uniform CT-tile KV chunks (CT=4 -> 1152 blocks, balanced), 512-thread /
// 8-wave blocks (4 heads x 2 q-halves share K/V stage). Double-buffered LDS
// staging with register prefetch: ONE barrier per tile; next tile's loads
// issue before compute (branchless, clamped) so stalls overlap across waves.
// T13 defer-max: skip O-rescale when per-tile max grows <= 8 (P <= 2^8).
// Compute core = R3-verified swapped 32x32 MFMA path.
template<int CT, bool SPLIT>
__global__ __launch_bounds__(512, 4)
void dllm_attn(const float* __restrict__ Qg, const float* __restrict__ Kg,
               const float* __restrict__ Vg, float* __restrict__ Og,
               char* __restrict__ Wg)
{
    __shared__ alignas(16) char kl[2 * 64 * 256];   // K [64][128] bf16 x2, XOR swz (k&7)<<4
    __shared__ alignas(16) char vl[2 * 128 * 128];  // V^T [128][64] bf16 x2, XOR swz (d&7)<<4

    const int RECS = (CT == 4) ? 140 : 72;
    const int bid = blockIdx.x;
    const int kh  = bid & 7;
    int tq2, ci, uu = 0;
    if (SPLIT){
        const int NU = (CT == 4) ? 144 : 80;
        uu = (NU - 1) - (bid >> 3);             // big chunks first
        int g = 0;
        #pragma unroll
        for (int gg = 1; gg < 8; ++gg)
            if ((CT * gg * (gg + 1)) / 2 <= uu) g = gg;
        const int rem = uu - (CT * g * (g + 1)) / 2;
        tq2 = CT * g + rem / (g + 1);
        ci  = rem % (g + 1);
    } else { tq2 = 31 - (bid >> 3); ci = 0; }
    const int ntt = tq2 + 1;                    // 64-key tiles for this q-block
    const int t0  = SPLIT ? (ci * CT) : 0;
    const int t1  = SPLIT ? min(t0 + CT, ntt) : ntt;
    const int nch = SPLIT ? (tq2 / CT + 1) : 1;

    const int tid = threadIdx.x;
    const int wv  = tid >> 6;                   // (half<<2)|hgrp
    const int ln  = tid & 63;
    const int lq  = ln & 31;
    const int hi  = ln >> 5;
    const int swz = (lq & 7) << 4;
    const int hgrp = wv & 3;
    const int half = wv >> 2;
    const int h   = (kh << 2) + hgrp;
    const int qw0 = (tq2 << 6) + (half << 5);
    const int nvis = qw0 + 32;

    const float QS = 0.088388347648318447f * 1.4426950408889634f; // SCALE*log2(e)
    short8 qf[8];
    {
        const float* qp = Qg + (size_t)(qw0 + lq) * 4096 + h * 128 + hi * 8;
        #pragma unroll
        for (int ds = 0; ds < 8; ++ds){
            const float4 a = *reinterpret_cast<const float4*>(qp + ds * 16);
            const float4 b = *reinterpret_cast<const float4*>(qp + ds * 16 + 4);
            qf[ds] = __builtin_bit_cast(short8,
                make_uint4(pk2(a.x * QS, a.y * QS), pk2(a.z * QS, a.w * QS),
                           pk2(b.x * QS, b.y * QS), pk2(b.z * QS, b.w * QS)));
        }
    }

    f32x16 oa[4];
    #pragma unroll
    for (int i = 0; i < 4; ++i)
        #pragma unroll
        for (int j = 0; j < 16; ++j) oa[i][j] = 0.f;
    float mR = -1e30f, lR = 0.f;

    // staging coords
    const int krow = tid >> 3;                  // key row 0..63
    const int kdc  = tid & 7;                   // 16-float d-chunk
    const int kkey = (krow & 7) << 4;
    const int vk0  = wv << 3;                   // wave's 8-key column block
    const int dA   = ln;                        // V^T rows dA, dA+64
    const int vkey = (dA & 7) << 4;

    u32 kpk[8], vpk[8];
    { // prologue: load+pack tile t0
        const int kv0 = t0 << 6;
        const float* kp = Kg + (size_t)(kv0 + krow) * 1024 + (kh << 7) + (kdc << 4);
        const float4 a = *reinterpret_cast<const float4*>(kp);
        const float4 b = *reinterpret_cast<const float4*>(kp + 4);
        const float4 c = *reinterpret_cast<const float4*>(kp + 8);
        const float4 d = *reinterpret_cast<const float4*>(kp + 12);
        kpk[0]=pk2(a.x,a.y); kpk[1]=pk2(a.z,a.w); kpk[2]=pk2(b.x,b.y); kpk[3]=pk2(b.z,b.w);
        kpk[4]=pk2(c.x,c.y); kpk[5]=pk2(c.z,c.w); kpk[6]=pk2(d.x,d.y); kpk[7]=pk2(d.z,d.w);
        const float* vp = Vg + (size_t)(kv0 + vk0) * 1024 + (kh << 7);
        float va[8], vb[8];
        #pragma unroll
        for (int j = 0; j < 8; ++j){ va[j] = vp[j*1024 + dA]; vb[j] = vp[j*1024 + 64 + dA]; }
        vpk[0]=pk2(va[0],va[1]); vpk[1]=pk2(va[2],va[3]); vpk[2]=pk2(va[4],va[5]); vpk[3]=pk2(va[6],va[7]);
        vpk[4]=pk2(vb[0],vb[1]); vpk[5]=pk2(vb[2],vb[3]); vpk[6]=pk2(vb[4],vb[5]); vpk[7]=pk2(vb[6],vb[7]);
    }

    int buf = 0;
    for (int t = t0; t < t1; ++t){
        const int kv0 = t << 6;
        const bool full = (kv0 + 64) <= nvis;   // wave-uniform

        // ---- phase A: write staged regs to LDS[buf] ----
        {
            const int kb = (buf << 14) + krow * 256;
            *reinterpret_cast<uint4*>(&kl[kb + ((kdc << 5) ^ kkey)]) =
                make_uint4(kpk[0], kpk[1], kpk[2], kpk[3]);
            *reinterpret_cast<uint4*>(&kl[kb + (((kdc << 5) + 16) ^ kkey)]) =
                make_uint4(kpk[4], kpk[5], kpk[6], kpk[7]);
            const int vb0 = (buf << 14);
            *reinterpret_cast<uint4*>(&vl[vb0 + dA * 128 + ((vk0 << 1) ^ vkey)]) =
                make_uint4(vpk[0], vpk[1], vpk[2], vpk[3]);
            *reinterpret_cast<uint4*>(&vl[vb0 + (dA + 64) * 128 + ((vk0 << 1) ^ vkey)]) =
                make_uint4(vpk[4], vpk[5], vpk[6], vpk[7]);
        }
        __syncthreads();

        // ---- phase B: issue next tile's loads + pack (clamped, branchless) ----
        {
            const int tn  = min(t + 1, t1 - 1);
            const int kvn = tn << 6;
            const float* kp = Kg + (size_t)(kvn + krow) * 1024 + (kh << 7) + (kdc << 4);
            const float4 a = *reinterpret_cast<const float4*>(kp);
            const float4 b = *reinterpret_cast<const float4*>(kp + 4);
            const float4 c = *reinterpret_cast<const float4*>(kp + 8);
            const float4 d = *reinterpret_cast<const float4*>(kp + 12);
            const float* vp = Vg + (size_t)(kvn + vk0) * 1024 + (kh << 7);
            float va[8], vb[8];
            #pragma unroll
            for (int j = 0; j < 8; ++j){ va[j] = vp[j*1024 + dA]; vb[j] = vp[j*1024 + 64 + dA]; }
            kpk[0]=pk2(a.x,a.y); kpk[1]=pk2(a.z,a.w); kpk[2]=pk2(b.x,b.y); kpk[3]=pk2(b.z,b.w);
            kpk[4]=pk2(c.x,c.y); kpk[5]=pk2(c.z,c.w); kpk[6]=pk2(d.x,d.y); kpk[7]=pk2(d.z,d.w);
            vpk[0]=pk2(va[0],va[1]); vpk[1]=pk2(va[2],va[3]); vpk[2]=pk2(va[4],va[5]); vpk[3]=pk2(va[6],va[7]);
            vpk[4]=pk2(vb[0],vb[1]); vpk[5]=pk2(vb[2],vb[3]); vpk[6]=pk2(vb[4],vb[5]); vpk[7]=pk2(vb[6],vb[7]);
        }

        // ---- phase C: compute tile t from LDS[buf] ----
        const int kb0 = buf << 14;
        f32x16 s0, s1;
        #pragma unroll
        for (int i = 0; i < 16; ++i){ s0[i] = 0.f; s1[i] = 0.f; }
        __builtin_amdgcn_s_setprio(1);
        #pragma unroll
        for (int ds = 0; ds < 8; ++ds){
            const short8 a0 = *reinterpret_cast<const short8*>(
                &kl[kb0 + lq * 256 + (((ds << 5) + (hi << 4)) ^ swz)]);
            s0 = __builtin_amdgcn_mfma_f32_32x32x16_bf16(a0, qf[ds], s0, 0, 0, 0);
        }
        if (full){
            #pragma unroll
            for (int ds = 0; ds < 8; ++ds){
                const short8 a1 = *reinterpret_cast<const short8*>(
                    &kl[kb0 + (32 + lq) * 256 + (((ds << 5) + (hi << 4)) ^ swz)]);
                s1 = __builtin_amdgcn_mfma_f32_32x32x16_bf16(a1, qf[ds], s1, 0, 0, 0);
            }
        }
        __builtin_amdgcn_s_setprio(0);

        // online softmax (lane-local per q=lq), T13 defer-max
        float p0[16], p1[16];
        float mx = -1e30f;
        #pragma unroll
        for (int r = 0; r < 16; ++r){ p0[r] = s0[r]; mx = fmaxf(mx, s0[r]); }
        if (full){
            #pragma unroll
            for (int r = 0; r < 16; ++r){ p1[r] = s1[r]; mx = fmaxf(mx, s1[r]); }
        }
        mx = fmaxf(mx, __shfl_xor(mx, 32, 64));
        float mn = fmaxf(mR, mx);
        if (__all(mx - mR <= 8.0f)){
            mn = mR;                               // defer: P bounded by 2^8
        } else {
            const float cf = __builtin_exp2f(mR - mn);
            lR *= cf;
            #pragma unroll
            for (int i = 0; i < 4; ++i)
                #pragma unroll
                for (int j = 0; j < 16; ++j) oa[i][j] *= cf;
            mR = mn;
        }
        float ps = 0.f;
        #pragma unroll
        for (int r = 0; r < 16; ++r){ p0[r] = __builtin_exp2f(p0[r] - mn); ps += p0[r]; }
        if (full){
            #pragma unroll
            for (int r = 0; r < 16; ++r){ p1[r] = __builtin_exp2f(p1[r] - mn); ps += p1[r]; }
        }
        ps += __shfl_xor(ps, 32, 64);
        lR += ps;

        // P^T -> bf16 words + partner exchange
        u32 pw0[8], px0[8], pw1[8], px1[8];
        #pragma unroll
        for (int rr = 0; rr < 8; ++rr){
            pw0[rr] = pk2(p0[2*rr], p0[2*rr+1]);
            px0[rr] = (u32)__shfl_xor((int)pw0[rr], 32, 64);
        }
        if (full){
            #pragma unroll
            for (int rr = 0; rr < 8; ++rr){
                pw1[rr] = pk2(p1[2*rr], p1[2*rr+1]);
                px1[rr] = (u32)__shfl_xor((int)pw1[rr], 32, 64);
            }
        }

        // build PV B-fragments
        short8 pf[4];
        #pragma unroll
        for (int ks = 0; ks < 4; ++ks){
            if (ks < 2 || full){
                const u32* pwt = (ks >> 1) ? pw1 : pw0;
                const u32* pxt = (ks >> 1) ? px1 : px0;
                u32 wb[4];
                #pragma unroll
                for (int w = 0; w < 4; ++w){
                    const int b = (w & 1) + ((ks & 1) << 2);
                    const u32 own = hi ? pwt[b + 2] : pwt[b];
                    const u32 oth = hi ? pxt[b + 2] : pxt[b];
                    wb[w] = (hi == (w >> 1)) ? own : oth;
                }
                pf[ks] = __builtin_bit_cast(short8, make_uint4(wb[0], wb[1], wb[2], wb[3]));
            }
        }

        // PV (swapped): O^T[d][q] += V^T[d][k] * P^T[k][q]
        __builtin_amdgcn_s_setprio(1);
        #pragma unroll
        for (int dt = 0; dt < 4; ++dt){
            #pragma unroll
            for (int ks = 0; ks < 4; ++ks){
                if (ks < 2 || full){
                    const short8 vf = *reinterpret_cast<const short8*>(
                        &vl[kb0 + ((dt << 5) + lq) * 128 + (((ks << 5) + (hi << 4)) ^ swz)]);
                    oa[dt] = __builtin_amdgcn_mfma_f32_32x32x16_bf16(vf, pf[ks], oa[dt], 0, 0, 0);
                }
            }
        }
        __builtin_amdgcn_s_setprio(0);
        buf ^= 1;
    }

    if (!SPLIT || nch == 1){
        const float rl = 1.f / lR;
        float* op = Og + (size_t)(qw0 + lq) * 4096 + (h << 7) + (hi << 2);
        #pragma unroll
        for (int dt = 0; dt < 4; ++dt){
            #pragma unroll
            for (int g2 = 0; g2 < 4; ++g2){
                float4 w4;
                w4.x = oa[dt][4*g2 + 0] * rl;
                w4.y = oa[dt][4*g2 + 1] * rl;
                w4.z = oa[dt][4*g2 + 2] * rl;
                w4.w = oa[dt][4*g2 + 3] * rl;
                *reinterpret_cast<float4*>(op + (dt << 5) + (g2 << 3)) = w4;
            }
        }
    } else {
        const int pu = ((kh * RECS + (uu - CT)) << 3) + wv;
        char* base = Wg + (size_t)pu * PART_STRIDE;
        #pragma unroll
        for (int i = 0; i < 8; ++i){
            const int e0 = i * 8;
            uint4 w4;
            w4.x = pk2(oa[(e0+0)>>4][(e0+0)&15], oa[(e0+1)>>4][(e0+1)&15]);
            w4.y = pk2(oa[(e0+2)>>4][(e0+2)&15], oa[(e0+3)>>4][(e0+3)&15]);
            w4.z = pk2(oa[(e0+4)>>4][(e0+4)&15], oa[(e0+5)>>4][(e0+5)&15]);
            w4.w = pk2(oa[(e0+6)>>4][(e0+6)&15], oa[(e0+7)>>4][(e0+7)&15]);
            *reinterpret_cast<uint4*>(base + ln * 128 + i * 16) = w4;
        }
        if (hi == 0){
            *reinterpret_cast<float*>(base + 8192 + lq * 4) = mR;
            *reinterpret_cast<float*>(base + 8320 + lq * 4) = lR;
        }
    }
}

// Merge: 256 thr/block, block = (q-head, tq2 >= CT, half). Record layout
// (R6/R7-verified): byte ln*128+i*16+k*4 holds (d,d+1), d=16i+8(k>>1)+2(k&1)+4(ln>>5).
template<int CT>
__global__ __launch_bounds__(256, 2)
void dllm_merge(float* __restrict__ Og, const char* __restrict__ Wg)
{
    const int RECS = (CT == 4) ? 140 : 72;
    const int MAXC = (CT == 4) ? 8 : 4;
    const int b    = blockIdx.x;
    const int h    = b & 31;
    const int r    = b >> 5;
    const int tq2  = CT + (r >> 1);
    const int half = r & 1;
    const int kh = h >> 2, hgrp = h & 3;
    const int wvIdx = (half << 2) | hgrp;
    const int g   = tq2 / CT;                // >= 1
    const int nch = g + 1;
    const int uu0 = (CT * g * (g + 1)) / 2 + (tq2 - CT * g) * (g + 1);

    const int tid = threadIdx.x;
    const int q   = tid >> 3;
    const int s   = tid & 7;

    const char* bases[8];
    float mv[8], lv[8];
    float M = -1e30f;
    #pragma unroll
    for (int c = 0; c < 8; ++c){
        if (c < MAXC && c < nch){
            bases[c] = Wg + (size_t)(((kh * RECS + uu0 - CT + c) << 3) + wvIdx) * PART_STRIDE;
            mv[c] = *reinterpret_cast<const float*>(bases[c] + 8192 + q * 4);
            lv[c] = *reinterpret_cast<const float*>(bases[c] + 8320 + q * 4);
            M = fmaxf(M, mv[c]);
        }
    }
    uint4 wlo[8], whi[8];
    #pragma unroll
    for (int c = 0; c < 8; ++c){
        if (c < MAXC && c < nch){
            wlo[c] = *reinterpret_cast<const uint4*>(bases[c] + q * 128 + s * 16);
            whi[c] = *reinterpret_cast<const uint4*>(bases[c] + (q + 32) * 128 + s * 16);
        }
    }
    float wsum = 0.f;
    float acc[16];
    #pragma unroll
    for (int e = 0; e < 16; ++e) acc[e] = 0.f;
    #pragma unroll
    for (int c = 0; c < 8; ++c){
        if (c < MAXC && c < nch){
            const float w = __builtin_exp2f(mv[c] - M);
            wsum += lv[c] * w;
            const u32 wl[4] = {wlo[c].x, wlo[c].y, wlo[c].z, wlo[c].w};
            const u32 wh[4] = {whi[c].x, whi[c].y, whi[c].z, whi[c].w};
            #pragma unroll
            for (int k = 0; k < 4; ++k){
                const int dl = ((k & 1) << 1) + ((k >> 1) << 3);   // 0,2,8,10
                acc[dl + 0] += b2f((u16)(wl[k] & 0xffffu)) * w;
                acc[dl + 1] += b2f((u16)(wl[k] >> 16)) * w;
                acc[dl + 4] += b2f((u16)(wh[k] & 0xffffu)) * w;
                acc[dl + 5] += b2f((u16)(wh[k] >> 16)) * w;
            }
        }
    }
    const float rl = 1.f / wsum;
    float* op = Og + (size_t)((tq2 << 6) + (half << 5) + q) * 4096 + h * 128 + (s << 4);
    #pragma unroll
    for (int gg = 0; gg < 4; ++gg){
        float4 v4;
        v4.x = acc[gg*4 + 0] * rl;
        v4.y = acc[gg*4 + 1] * rl;
        v4.z = acc[gg*4 + 2] * rl;
        v4.w = acc[gg*4 + 3] * rl;
        *reinterpret_cast<float4*>(op + (gg << 2)) = v4;
    }
}

extern "C" void kernel_launch(void* const* d_in, const int* in_sizes, int n_in,
                              void* d_out, int out_size, void* d_ws, size_t ws_size,
                              hipStream_t stream) {
    const float* Q = (const float*)d_in[0];
    const float* K = (const float*)d_in[1];
    const float* V = (const float*)d_in[2];
    float* O = (float*)d_out;
    const size_t need4 = (size_t)8 * 140 * 8 * PART_STRIDE;   // 75.7 MB
    const size_t need8 = (size_t)8 *  72 * 8 * PART_STRIDE;   // 38.9 MB
    if (ws_size >= need4){
        dllm_attn<4, true><<<dim3(1152), dim3(512), 0, stream>>>(Q, K, V, O, (char*)d_ws);
        dllm_merge<4><<<dim3(1792), dim3(256), 0, stream>>>(O, (const char*)d_ws);
    } else if (ws_size >= need8){
        dllm_attn<8, true><<<dim3(640), dim3(512), 0, stream>>>(Q, K, V, O, (char*)d_ws);
        dllm_merge<8><<<dim3(1536), dim3(256), 0, stream>>>(O, (const char*)d_ws);
    } else {
        dllm_attn<4, false><<<dim3(256), dim3(512), 0, stream>>>(Q, K, V, O, (char*)d_ws);
    }
}